// Round 1
// baseline (837.948 us; speedup 1.0000x reference)
//
#include <hip/hip_runtime.h>
#include <math.h>

#define N_NODES 100000
#define N_EDGES 1600000
#define NGR 64
#define IMG_F 50176
#define NCLS 38
#define KSPLIT 98

typedef short bf16x8 __attribute__((ext_vector_type(8)));
typedef float f32x4 __attribute__((ext_vector_type(4)));
typedef unsigned int uint;

// fp32 pair -> packed bf16x2 (RNE)
__device__ __forceinline__ uint pk2(float a, float b) {
  uint ua = __float_as_uint(a), ub = __float_as_uint(b);
  ua = (ua + 0x7fffu + ((ua >> 16) & 1u)) >> 16;
  ub = (ub + 0x7fffu + ((ub >> 16) & 1u)) >> 16;
  return ua | (ub << 16);
}
__device__ __forceinline__ unsigned short f2bf(float x) {
  uint u = __float_as_uint(x);
  u = (u + 0x7fffu + ((u >> 16) & 1u)) >> 16;
  return (unsigned short)u;
}
__device__ __forceinline__ float bflo(uint u) { return __uint_as_float(u << 16); }
__device__ __forceinline__ float bfhi(uint u) { return __uint_as_float(u & 0xffff0000u); }

// ---------------- small helpers ----------------
__device__ __forceinline__ int lower_bound_i(const int* __restrict__ a, int n, int v) {
  int lo = 0, hi = n;
  while (lo < hi) { int mid = (lo + hi) >> 1; if (a[mid] < v) lo = mid + 1; else hi = mid; }
  return lo;
}

__global__ void k_deg(const int* __restrict__ dst, int* __restrict__ deg) {
  int e = blockIdx.x * 256 + threadIdx.x;
  if (e < N_EDGES) atomicAdd(&deg[dst[e]], 1);
}

__global__ void k_dinv(const int* __restrict__ deg, float* __restrict__ dinv) {
  int n = blockIdx.x * 256 + threadIdx.x;
  if (n < N_NODES) dinv[n] = rsqrtf((float)deg[n] + 1.0f);
}

// ---------------- block scan: rowptr = exclusive_scan(deg) ----------------
#define SCAN_CHUNK 512
#define SCAN_BLOCKS ((N_NODES + SCAN_CHUNK - 1) / SCAN_CHUNK)  // 196

__global__ __launch_bounds__(512)
void k_scan1(const int* __restrict__ deg, int* __restrict__ bsum) {
  __shared__ int s[512];
  int t = threadIdx.x;
  int i = blockIdx.x * SCAN_CHUNK + t;
  s[t] = (i < N_NODES) ? deg[i] : 0;
  __syncthreads();
  for (int off = 256; off > 0; off >>= 1) {
    if (t < off) s[t] += s[t + off];
    __syncthreads();
  }
  if (t == 0) bsum[blockIdx.x] = s[0];
}

__global__ __launch_bounds__(256)
void k_scan2(const int* __restrict__ bsum, int* __restrict__ boff) {
  __shared__ int s[256];
  int t = threadIdx.x;
  s[t] = (t < SCAN_BLOCKS) ? bsum[t] : 0;
  __syncthreads();
  for (int off = 1; off < 256; off <<= 1) {
    int v = (t >= off) ? s[t - off] : 0;
    __syncthreads();
    s[t] += v;
    __syncthreads();
  }
  if (t < SCAN_BLOCKS) boff[t] = (t == 0) ? 0 : s[t - 1];
}

__global__ __launch_bounds__(512)
void k_scan3(const int* __restrict__ deg, const int* __restrict__ boff,
             int* __restrict__ rowptr, int* __restrict__ cur) {
  __shared__ int s[512];
  int t = threadIdx.x;
  int i = blockIdx.x * SCAN_CHUNK + t;
  int d = (i < N_NODES) ? deg[i] : 0;
  s[t] = d;
  __syncthreads();
  for (int off = 1; off < 512; off <<= 1) {
    int v = (t >= off) ? s[t - off] : 0;
    __syncthreads();
    s[t] += v;
    __syncthreads();
  }
  if (i < N_NODES) {
    int v = boff[blockIdx.x] + s[t] - d;
    rowptr[i] = v;
    cur[i] = v;  // cursor copy: csr_fill needs only one atomicAdd per edge
  }
  if (blockIdx.x == 0 && t == 0) rowptr[N_NODES] = N_EDGES;
}

__global__ void k_csr_fill(const int* __restrict__ src, const int* __restrict__ dst,
                           int* __restrict__ cur, int* __restrict__ csr_src) {
  int e = blockIdx.x * 256 + threadIdx.x;
  if (e >= N_EDGES) return;
  int pos = atomicAdd(&cur[dst[e]], 1);
  csr_src[pos] = src[e];
}

// ---------------- GCN aggregation (gather, bf16, atomic-free) ----------------
// One node per L-lane group (L=64: full wave, zero divergence; L=32: half wave).
// Each lane owns one uint (2 bf16 features). Per neighbor: one coalesced 4B/lane
// load (256B/row for L=64). Unroll-4 keeps 4 gathers in flight per group.
template<int L>
__global__ __launch_bounds__(256)
void k_agg_wave(const unsigned short* __restrict__ h, const float* __restrict__ dinv,
                const int* __restrict__ rowptr, const int* __restrict__ csr_src,
                unsigned short* __restrict__ out) {
  constexpr int NPB = 256 / L;
  int n = blockIdx.x * NPB + threadIdx.x / L;
  int lane = threadIdx.x % L;
  if (n >= N_NODES) return;
  const uint* hu = (const uint*)h;
  uint r0 = hu[(size_t)n * L + lane];
  float aL = bflo(r0), aH = bfhi(r0);
  int lo = rowptr[n], hi = rowptr[n + 1];
  int i = lo;
  for (; i + 4 <= hi; i += 4) {
    int s0 = csr_src[i], s1 = csr_src[i + 1];
    int s2 = csr_src[i + 2], s3 = csr_src[i + 3];
    uint a0 = hu[(size_t)s0 * L + lane];
    uint a1 = hu[(size_t)s1 * L + lane];
    uint a2 = hu[(size_t)s2 * L + lane];
    uint a3 = hu[(size_t)s3 * L + lane];
    aL += bflo(a0) + bflo(a1) + bflo(a2) + bflo(a3);
    aH += bfhi(a0) + bfhi(a1) + bfhi(a2) + bfhi(a3);
  }
  for (; i < hi; i++) {
    uint a0 = hu[(size_t)csr_src[i] * L + lane];
    aL += bflo(a0);
    aH += bfhi(a0);
  }
  float dn = dinv[n];
  ((uint*)out)[(size_t)n * L + lane] = pk2(dn * aL, dn * aH);
}

// ---------------- img GEMM: bf16 MFMA split-K, NO atomics ----------------
// 4 column blocks of 256 (A re-read 4x instead of 8x), 98 K-slabs of 512.
__global__ __launch_bounds__(256)
void k_img_mfma(const float* __restrict__ A, const float* __restrict__ B,
                float* __restrict__ partial) {
  __shared__ __align__(16) short Al[512 * 8];    // 8 KB  (64 rows x 64 k)
  __shared__ __align__(16) short Bl[2048 * 8];   // 32 KB (64 k x 256 cols)
  const int tid = threadIdx.x;
  const int l = tid & 63, w = tid >> 6;
  const int col0 = blockIdx.x * 256;
  const int kbase = blockIdx.y * 512;
  const int kq_l = l >> 4, rr_l = l & 15;
  f32x4 acc[16];
#pragma unroll
  for (int ct = 0; ct < 16; ct++) acc[ct] = (f32x4)(0.f);

  for (int st = 0; st < 8; st++) {
    int k0 = kbase + st * 64;
    __syncthreads();
#pragma unroll
    for (int it = 0; it < 2; it++) {
      int c = tid + it * 256;
      int r = c >> 3, ko = c & 7;
      const float* ap = &A[(size_t)r * IMG_F + k0 + ko * 8];
      float4 f0 = *(const float4*)ap;
      float4 f1 = *(const float4*)(ap + 4);
      int kst = ko >> 2, kq = ko & 3, rt = r >> 4, rr = r & 15;
      int ci = ((kst * 4 + kq) * 4 + (rt ^ kq)) * 16 + rr;
      uint4 u = make_uint4(pk2(f0.x, f0.y), pk2(f0.z, f0.w),
                           pk2(f1.x, f1.y), pk2(f1.z, f1.w));
      *(uint4*)&Al[ci * 8] = u;
    }
    {
      int col4 = tid & 63, koB = tid >> 6;  // col4: 0..63 (x4 cols), koB: 0..3
#pragma unroll
      for (int itb = 0; itb < 2; itb++) {
        int ko = koB + itb * 4;             // 0..7 (x8 k-rows)
        const float* bp = &B[(size_t)(k0 + ko * 8) * 1024 + col0 + col4 * 4];
        float fb[8][4];
#pragma unroll
        for (int i2 = 0; i2 < 8; i2++)
          *(float4*)&fb[i2][0] = *(const float4*)(bp + (size_t)i2 * 1024);
        int kst = ko >> 2, kq = ko & 3;
#pragma unroll
        for (int c2 = 0; c2 < 4; c2++) {
          int col = col4 * 4 + c2;
          int ct = col >> 4, colin = col & 15;
          int ci = ((kst * 4 + kq) * 16 + (ct ^ kq)) * 16 + colin;
          uint4 u = make_uint4(pk2(fb[0][c2], fb[1][c2]), pk2(fb[2][c2], fb[3][c2]),
                               pk2(fb[4][c2], fb[5][c2]), pk2(fb[6][c2], fb[7][c2]));
          *(uint4*)&Bl[ci * 8] = u;
        }
      }
    }
    __syncthreads();
#pragma unroll
    for (int kst = 0; kst < 2; kst++) {
      bf16x8 af = *(bf16x8*)&Al[(((kst * 4 + kq_l) * 4 + (w ^ kq_l)) * 16 + rr_l) * 8];
#pragma unroll
      for (int ct = 0; ct < 16; ct++) {
        bf16x8 bf = *(bf16x8*)&Bl[(((kst * 4 + kq_l) * 16 + (ct ^ kq_l)) * 16 + rr_l) * 8];
        acc[ct] = __builtin_amdgcn_mfma_f32_16x16x32_bf16(af, bf, acc[ct], 0, 0, 0);
      }
    }
  }
  float* P = partial + (size_t)blockIdx.y * 64 * 1024;
#pragma unroll
  for (int ct = 0; ct < 16; ct++)
#pragma unroll
    for (int rg = 0; rg < 4; rg++) {
      int row = w * 16 + (l >> 4) * 4 + rg;
      int col = col0 + ct * 16 + (l & 15);
      P[row * 1024 + col] = acc[ct][rg];
    }
}

__global__ __launch_bounds__(256)
void k_img_reduce(const float* __restrict__ partial, const float* __restrict__ bm0,
                  float* __restrict__ tmp1) {
  int i = blockIdx.x * 256 + threadIdx.x;
  float s = bm0[i & 1023];
  for (int ks = 0; ks < KSPLIT; ks++) s += partial[(size_t)ks * 65536 + i];
  tmp1[i] = s;
}

__global__ __launch_bounds__(256)
void k_img_gemm2(const float* __restrict__ T, const float* __restrict__ Wm1,
                 const float* __restrict__ bm1, float* __restrict__ x0) {
  int r = blockIdx.x;
  int c = threadIdx.x & 63;
  int q = threadIdx.x >> 6;
  float acc = 0.f;
#pragma unroll 8
  for (int k = q; k < 1024; k += 4)
    acc = fmaf(T[r * 1024 + k], Wm1[k * 64 + c], acc);
  __shared__ float red[4][64];
  red[q][c] = acc;
  __syncthreads();
  if (q == 0) x0[r * 64 + c] = red[0][c] + red[1][c] + red[2][c] + red[3][c] + bm1[c];
}

// ---------------- node GEMM: C[M,N] = dinv[row]*(act(A[M,128]) @ W[128,N]), bf16
template<int N, bool RELU_BIAS, bool BF16_IN>
__global__ __launch_bounds__(256)
void k_gcn_mfma(const void* __restrict__ Ain, const float* __restrict__ W,
                const float* __restrict__ abias, const float* __restrict__ dinv,
                unsigned short* __restrict__ C, int M) {
  constexpr int NT16 = N / 16;
  __shared__ __align__(16) short Al[1024 * 8];
  __shared__ __align__(16) short Wl[256 * NT16 * 8];
  const int tid = threadIdx.x;
  const int l = tid & 63, w = tid >> 6;
  const int row0 = blockIdx.x * 64;
  const int kq_l = l >> 4, rr_l = l & 15;

#pragma unroll
  for (int it = 0; it < 4; it++) {
    int c = tid + it * 256;
    int r = c >> 4, ko = c & 15;
    int row = row0 + r;
    float f[8] = {0.f, 0.f, 0.f, 0.f, 0.f, 0.f, 0.f, 0.f};
    if (row < M) {
      if constexpr (BF16_IN) {
        const uint* ap = (const uint*)Ain + (size_t)row * 64 + ko * 4;
        uint4 u = *(const uint4*)ap;
        f[0] = bflo(u.x); f[1] = bfhi(u.x); f[2] = bflo(u.y); f[3] = bfhi(u.y);
        f[4] = bflo(u.z); f[5] = bfhi(u.z); f[6] = bflo(u.w); f[7] = bfhi(u.w);
      } else {
        const float* ap = (const float*)Ain + (size_t)row * 128 + ko * 8;
        *(float4*)&f[0] = *(const float4*)ap;
        *(float4*)&f[4] = *(const float4*)(ap + 4);
      }
      if (RELU_BIAS) {
        const float* bp = &abias[ko * 8];
#pragma unroll
        for (int j = 0; j < 8; j++) f[j] = fmaxf(f[j] + bp[j], 0.f);
      }
    }
    int kst = ko >> 2, kq = ko & 3, rt = r >> 4, rr = r & 15;
    int ci = ((kst * 4 + kq) * 4 + (rt ^ kq)) * 16 + rr;
    uint4 u = make_uint4(pk2(f[0], f[1]), pk2(f[2], f[3]),
                         pk2(f[4], f[5]), pk2(f[6], f[7]));
    *(uint4*)&Al[ci * 8] = u;
  }
#pragma unroll
  for (int it = 0; it < (N == 128 ? 2 : 1); it++) {
    int mt = tid + it * 256;
    int col4 = mt % (N / 4), ko = mt / (N / 4);
    float fb[8][4];
#pragma unroll
    for (int i2 = 0; i2 < 8; i2++)
      *(float4*)&fb[i2][0] = *(const float4*)&W[(size_t)(ko * 8 + i2) * N + col4 * 4];
    int kst = ko >> 2, kq = ko & 3;
#pragma unroll
    for (int c2 = 0; c2 < 4; c2++) {
      int col = col4 * 4 + c2;
      int ct = col >> 4, colin = col & 15;
      int ci = ((kst * 4 + kq) * NT16 + (ct ^ kq)) * 16 + colin;
      uint4 u = make_uint4(pk2(fb[0][c2], fb[1][c2]), pk2(fb[2][c2], fb[3][c2]),
                           pk2(fb[4][c2], fb[5][c2]), pk2(fb[6][c2], fb[7][c2]));
      *(uint4*)&Wl[ci * 8] = u;
    }
  }
  __syncthreads();

  f32x4 acc[NT16];
#pragma unroll
  for (int ct = 0; ct < NT16; ct++) acc[ct] = (f32x4)(0.f);
#pragma unroll
  for (int kst = 0; kst < 4; kst++) {
    bf16x8 af = *(bf16x8*)&Al[(((kst * 4 + kq_l) * 4 + (w ^ kq_l)) * 16 + rr_l) * 8];
#pragma unroll
    for (int ct = 0; ct < NT16; ct++) {
      bf16x8 bf = *(bf16x8*)&Wl[(((kst * 4 + kq_l) * NT16 + (ct ^ kq_l)) * 16 + rr_l) * 8];
      acc[ct] = __builtin_amdgcn_mfma_f32_16x16x32_bf16(af, bf, acc[ct], 0, 0, 0);
    }
  }
#pragma unroll
  for (int rg = 0; rg < 4; rg++) {
    int row = row0 + w * 16 + (l >> 4) * 4 + rg;
    if (row < M) {
      float dsc = dinv[row];
#pragma unroll
      for (int ct = 0; ct < NT16; ct++)
        C[(size_t)row * N + ct * 16 + (l & 15)] = f2bf(acc[ct][rg] * dsc);
    }
  }
}

// ---------------- pool (bf16 input, + bias + relu) ----------------
__global__ __launch_bounds__(256)
void k_pool(const unsigned short* __restrict__ h2, const float* __restrict__ b2,
            const int* __restrict__ batch, float* __restrict__ g) {
  int b = blockIdx.x;
  int f = threadIdx.x & 63;
  int q = threadIdx.x >> 6;
  int lo = lower_bound_i(batch, N_NODES, b);
  int hi = lower_bound_i(batch, N_NODES, b + 1);
  float bias = b2[f];
  float acc = 0.f;
  for (int i = lo + q; i < hi; i += 4)
    acc += fmaxf(__uint_as_float((uint)h2[(size_t)i * 64 + f] << 16) + bias, 0.f);
  __shared__ float red[4][64];
  red[q][f] = acc;
  __syncthreads();
  if (q == 0) g[b * 64 + f] = red[0][f] + red[1][f] + red[2][f] + red[3][f];
}

// ---------------- head ----------------
__global__ __launch_bounds__(64)
void k_final(const float* __restrict__ x0, const float* __restrict__ g,
             const float* __restrict__ Wmx, const float* __restrict__ bmx,
             const float* __restrict__ Wfc, const float* __restrict__ bfc,
             float* __restrict__ out) {
  int r = blockIdx.x;
  int c = threadIdx.x;
  __shared__ float sx[128];
  __shared__ float slog[NCLS];
  __shared__ float sred;
  float acc = bmx[c];
#pragma unroll 8
  for (int k = 0; k < 64; k++) acc = fmaf(g[r * 64 + k], Wmx[k * 64 + c], acc);
  sx[64 + c] = acc;
  sx[c] = x0[r * 64 + c];
  __syncthreads();
  float lg = 0.f;
  if (c < NCLS) {
    lg = bfc[c];
#pragma unroll 8
    for (int k = 0; k < 128; k++) lg = fmaf(sx[k], Wfc[k * NCLS + c], lg);
    slog[c] = lg;
  }
  __syncthreads();
  if (c == 0) {
    float m = -1e30f;
    for (int j = 0; j < NCLS; j++) m = fmaxf(m, slog[j]);
    float s = 0.f;
    for (int j = 0; j < NCLS; j++) s += expf(slog[j] - m);
    sred = m + logf(s);
  }
  __syncthreads();
  if (c < NCLS) out[r * NCLS + c] = lg - sred;
}

// ---------------- launch ----------------
extern "C" void kernel_launch(void* const* d_in, const int* in_sizes, int n_in,
                              void* d_out, int out_size, void* d_ws, size_t ws_size,
                              hipStream_t stream) {
  const float* x    = (const float*)d_in[0];
  const int*   edge = (const int*)d_in[1];
  const float* img  = (const float*)d_in[2];
  const int*   batch= (const int*)d_in[3];
  const float* W1   = (const float*)d_in[4];
  const float* b1   = (const float*)d_in[5];
  const float* W2   = (const float*)d_in[6];
  const float* b2   = (const float*)d_in[7];
  const float* Wm0  = (const float*)d_in[8];
  const float* bm0  = (const float*)d_in[9];
  const float* Wm1  = (const float*)d_in[10];
  const float* bm1  = (const float*)d_in[11];
  const float* Wmx  = (const float*)d_in[12];
  const float* bmx  = (const float*)d_in[13];
  const float* Wfc  = (const float*)d_in[14];
  const float* bfc  = (const float*)d_in[15];
  float* out = (float*)d_out;
  const int* srcp = edge;
  const int* dstp = edge + N_EDGES;

  char* ws = (char*)d_ws;
  size_t off = 0;
  auto alloc = [&](size_t bytes) {
    void* p = ws + off;
    off += (bytes + 255) & ~(size_t)255;
    return p;
  };
  int*   deg    = (int*)  alloc((size_t)N_NODES * 4);
  int*   cur    = (int*)  alloc((size_t)N_NODES * 4);
  float* dinv   = (float*)alloc((size_t)N_NODES * 4);
  int*   rowptr = (int*)  alloc((size_t)(N_NODES + 1) * 4);
  int*   bsum   = (int*)  alloc((size_t)SCAN_BLOCKS * 4);
  int*   boff   = (int*)  alloc((size_t)SCAN_BLOCKS * 4);
  int*   csr    = (int*)  alloc((size_t)N_EDGES * 4);
  unsigned short* bufA = (unsigned short*)alloc((size_t)N_NODES * 128 * 2);
  size_t bufB_bytes = (size_t)KSPLIT * 65536 * 4;               // >= N_NODES*128*2
  unsigned short* bufB = (unsigned short*)alloc(bufB_bytes);
  float* tmp1   = (float*)alloc(64 * 1024 * 4);
  float* x0     = (float*)alloc(64 * 64 * 4);
  float* g      = (float*)alloc(64 * 64 * 4);
  float* partial = (float*)bufB;  // used only before agg1 writes bufB (stream-ordered)
  (void)ws_size; (void)in_sizes; (void)n_in; (void)out_size;

  // degrees -> dinv ; rowptr (+cursor copy) ; CSR fill (single atomic per edge)
  hipMemsetAsync(deg, 0, (size_t)N_NODES * 4, stream);
  k_deg  <<<(N_EDGES + 255) / 256, 256, 0, stream>>>(dstp, deg);
  k_dinv <<<(N_NODES + 255) / 256, 256, 0, stream>>>(deg, dinv);
  k_scan1<<<SCAN_BLOCKS, 512, 0, stream>>>(deg, bsum);
  k_scan2<<<1, 256, 0, stream>>>(bsum, boff);
  k_scan3<<<SCAN_BLOCKS, 512, 0, stream>>>(deg, boff, rowptr, cur);
  k_csr_fill<<<(N_EDGES + 255) / 256, 256, 0, stream>>>(srcp, dstp, cur, csr);

  // image branch (bf16 MFMA split-K, 4 col-blocks; partials + reduce; no atomics)
  k_img_mfma  <<<dim3(4, KSPLIT), 256, 0, stream>>>(img, Wm0, partial);
  k_img_reduce<<<256, 256, 0, stream>>>(partial, bm0, tmp1);
  k_img_gemm2 <<<64, 256, 0, stream>>>(tmp1, Wm1, bm1, x0);

  // GCN layer 1: h1' = dinv*(x @ W1) in bf16 ; gather-agg (1 node / wave)
  k_gcn_mfma<128, false, false><<<(N_NODES + 63) / 64, 256, 0, stream>>>(
      x, W1, nullptr, dinv, bufA, N_NODES);
  k_agg_wave<64><<<(N_NODES + 3) / 4, 256, 0, stream>>>(
      bufA, dinv, rowptr, csr, bufB);

  // GCN layer 2: h2' = dinv*(relu(agg1 + b1) @ W2) in bf16 ; gather-agg
  k_gcn_mfma<64, true, true><<<(N_NODES + 63) / 64, 256, 0, stream>>>(
      bufB, W2, b1, dinv, bufA, N_NODES);
  k_agg_wave<32><<<(N_NODES + 7) / 8, 256, 0, stream>>>(
      bufA, dinv, rowptr, csr, bufB);

  // pool + head
  k_pool <<<NGR, 256, 0, stream>>>(bufB, b2, batch, g);
  k_final<<<NGR, 64, 0, stream>>>(x0, g, Wmx, bmx, Wfc, bfc, out);
}

// Round 2
// 664.271 us; speedup vs baseline: 1.2615x; 1.2615x over previous
//
#include <hip/hip_runtime.h>
#include <math.h>

#define N_NODES 100000
#define N_EDGES 1600000
#define NGR 64
#define IMG_F 50176
#define NCLS 38
#define KSPLIT 98

// bucketed CSR build
#define BSHIFT 9
#define NBUCK 196        // ceil(100000 / 512)
#define BCAP 9216        // per-bucket edge capacity (mean 8192, sd ~90 -> +11 sigma)
#define EPB 16           // edges per thread in k_bucket (4096 / block)

typedef short bf16x8 __attribute__((ext_vector_type(8)));
typedef float f32x4 __attribute__((ext_vector_type(4)));
typedef unsigned int uint;

// fp32 pair -> packed bf16x2 (RNE)
__device__ __forceinline__ uint pk2(float a, float b) {
  uint ua = __float_as_uint(a), ub = __float_as_uint(b);
  ua = (ua + 0x7fffu + ((ua >> 16) & 1u)) >> 16;
  ub = (ub + 0x7fffu + ((ub >> 16) & 1u)) >> 16;
  return ua | (ub << 16);
}
__device__ __forceinline__ unsigned short f2bf(float x) {
  uint u = __float_as_uint(x);
  u = (u + 0x7fffu + ((u >> 16) & 1u)) >> 16;
  return (unsigned short)u;
}
__device__ __forceinline__ float bflo(uint u) { return __uint_as_float(u << 16); }
__device__ __forceinline__ float bfhi(uint u) { return __uint_as_float(u & 0xffff0000u); }

__device__ __forceinline__ int lower_bound_i(const int* __restrict__ a, int n, int v) {
  int lo = 0, hi = n;
  while (lo < hi) { int mid = (lo + hi) >> 1; if (a[mid] < v) lo = mid + 1; else hi = mid; }
  return lo;
}

// ---------------- pass 1: coarse-bucket the edges ----------------
// 196 buckets of 512 nodes (dst>>9). LDS histogram -> one region-reserve atomic
// per (block,bucket) -> contiguous scatter of (src,dst) pairs into bucket slack.
__global__ __launch_bounds__(256)
void k_bucket(const int* __restrict__ src, const int* __restrict__ dst,
              int* __restrict__ gcnt, uint2* __restrict__ ebuf) {
  __shared__ int hist[NBUCK];
  __shared__ int base[NBUCK];
  const int t = threadIdx.x;
  if (t < NBUCK) hist[t] = 0;
  __syncthreads();
  const int e0 = blockIdx.x * (EPB * 256);
  int s[EPB], d[EPB];
#pragma unroll
  for (int j = 0; j < EPB; j++) {
    int e = e0 + j * 256 + t;
    if (e < N_EDGES) {
      s[j] = src[e];
      d[j] = dst[e];
      atomicAdd(&hist[d[j] >> BSHIFT], 1);
    } else {
      d[j] = -1;
    }
  }
  __syncthreads();
  if (t < NBUCK) base[t] = atomicAdd(&gcnt[t], hist[t]);
  __syncthreads();
#pragma unroll
  for (int j = 0; j < EPB; j++) {
    if (d[j] >= 0) {
      int key = d[j] >> BSHIFT;
      int pos = atomicAdd(&base[key], 1);
      if (pos < BCAP)
        ebuf[(size_t)key * BCAP + pos] = make_uint2((uint)s[j], (uint)d[j]);
    }
  }
}

// ---------------- pass 2: per-bucket CSR fill, deg/row_lo/dinv ----------------
// One block per bucket. LDS histogram of 512 local nodes, LDS scan, LDS-cursor
// scatter into the bucket's contiguous csr region (full-line writes).
__global__ __launch_bounds__(512)
void k_binfill(const uint2* __restrict__ ebuf, const int* __restrict__ gcnt,
               int* __restrict__ deg, int* __restrict__ row_lo,
               float* __restrict__ dinv, int* __restrict__ csr) {
  __shared__ int sdeg[512];
  __shared__ int sscan[512];
  __shared__ int scur[512];
  const int b = blockIdx.x, t = threadIdx.x;
  int cnt = gcnt[b];
  if (cnt > BCAP) cnt = BCAP;
  sdeg[t] = 0;
  __syncthreads();
  const uint2* eb = ebuf + (size_t)b * BCAP;
  for (int i = t; i < cnt; i += 512)
    atomicAdd(&sdeg[eb[i].y & 511], 1);
  __syncthreads();
  int d = sdeg[t];
  sscan[t] = d;
  __syncthreads();
  for (int off = 1; off < 512; off <<= 1) {
    int v = (t >= off) ? sscan[t - off] : 0;
    __syncthreads();
    sscan[t] += v;
    __syncthreads();
  }
  int excl = sscan[t] - d;
  int n = b * 512 + t;
  if (n < N_NODES) {
    deg[n] = d;
    row_lo[n] = b * BCAP + excl;
    dinv[n] = rsqrtf((float)d + 1.0f);
  }
  scur[t] = excl;
  __syncthreads();
  for (int i = t; i < cnt; i += 512) {
    uint2 e = eb[i];
    int off2 = atomicAdd(&scur[e.y & 511], 1);
    csr[(size_t)b * BCAP + off2] = (int)e.x;
  }
}

// ---------------- GCN aggregation (gather, bf16, atomic-free) ----------------
// h holds h'[n] = h_lin[n]*dinv[n] (bf16). out[n] = bf16(dinv[n]*(h'[n]+sum h'[src])).
// 16 lanes per node (4 nodes/wave: 1KB gathered per wave-instruction), unroll-4.
template<int F, int VEC>
__global__ __launch_bounds__(256)
void k_agg_bf16(const unsigned short* __restrict__ h, const float* __restrict__ dinv,
                const int* __restrict__ row_lo, const int* __restrict__ deg,
                const int* __restrict__ csr_src, unsigned short* __restrict__ out) {
  constexpr int L = F / VEC;    // 16
  constexpr int NPB = 256 / L;  // 16
  constexpr int NU = VEC / 2;   // uints per lane
  int n = blockIdx.x * NPB + threadIdx.x / L;
  int lane = threadIdx.x % L;
  if (n >= N_NODES) return;
  const uint* hu = (const uint*)h;
  const int rs = F / 2;  // uints per feature row
  float acc[VEC];
  uint r0[NU];
  if constexpr (VEC == 8) *(uint4*)r0 = *(const uint4*)&hu[(size_t)n * rs + lane * NU];
  else                    *(uint2*)r0 = *(const uint2*)&hu[(size_t)n * rs + lane * NU];
#pragma unroll
  for (int j = 0; j < NU; j++) { acc[2*j] = bflo(r0[j]); acc[2*j+1] = bfhi(r0[j]); }
  int lo = row_lo[n], hi = lo + deg[n];
  int i = lo;
  for (; i + 4 <= hi; i += 4) {
    int s0 = csr_src[i], s1 = csr_src[i + 1];
    int s2 = csr_src[i + 2], s3 = csr_src[i + 3];
    uint a0[NU], a1[NU], a2[NU], a3[NU];
    if constexpr (VEC == 8) {
      *(uint4*)a0 = *(const uint4*)&hu[(size_t)s0 * rs + lane * NU];
      *(uint4*)a1 = *(const uint4*)&hu[(size_t)s1 * rs + lane * NU];
      *(uint4*)a2 = *(const uint4*)&hu[(size_t)s2 * rs + lane * NU];
      *(uint4*)a3 = *(const uint4*)&hu[(size_t)s3 * rs + lane * NU];
    } else {
      *(uint2*)a0 = *(const uint2*)&hu[(size_t)s0 * rs + lane * NU];
      *(uint2*)a1 = *(const uint2*)&hu[(size_t)s1 * rs + lane * NU];
      *(uint2*)a2 = *(const uint2*)&hu[(size_t)s2 * rs + lane * NU];
      *(uint2*)a3 = *(const uint2*)&hu[(size_t)s3 * rs + lane * NU];
    }
#pragma unroll
    for (int j = 0; j < NU; j++) {
      acc[2*j]   += bflo(a0[j]) + bflo(a1[j]) + bflo(a2[j]) + bflo(a3[j]);
      acc[2*j+1] += bfhi(a0[j]) + bfhi(a1[j]) + bfhi(a2[j]) + bfhi(a3[j]);
    }
  }
  for (; i < hi; i++) {
    int s0 = csr_src[i];
    uint a0[NU];
    if constexpr (VEC == 8) *(uint4*)a0 = *(const uint4*)&hu[(size_t)s0 * rs + lane * NU];
    else                    *(uint2*)a0 = *(const uint2*)&hu[(size_t)s0 * rs + lane * NU];
#pragma unroll
    for (int j = 0; j < NU; j++) { acc[2*j] += bflo(a0[j]); acc[2*j+1] += bfhi(a0[j]); }
  }
  float dn = dinv[n];
  uint o[NU];
#pragma unroll
  for (int j = 0; j < NU; j++) o[j] = pk2(dn * acc[2*j], dn * acc[2*j+1]);
  uint* op = (uint*)out + (size_t)n * rs + lane * NU;
  if constexpr (VEC == 8) *(uint4*)op = *(uint4*)o;
  else                    *(uint2*)op = *(uint2*)o;
}

// ---------------- img GEMM: bf16 MFMA split-K, NO atomics ----------------
// 4 column blocks of 256 (A re-read 4x), 98 K-slabs of 512.
__global__ __launch_bounds__(256)
void k_img_mfma(const float* __restrict__ A, const float* __restrict__ B,
                float* __restrict__ partial) {
  __shared__ __align__(16) short Al[512 * 8];    // 8 KB  (64 rows x 64 k)
  __shared__ __align__(16) short Bl[2048 * 8];   // 32 KB (64 k x 256 cols)
  const int tid = threadIdx.x;
  const int l = tid & 63, w = tid >> 6;
  const int col0 = blockIdx.x * 256;
  const int kbase = blockIdx.y * 512;
  const int kq_l = l >> 4, rr_l = l & 15;
  f32x4 acc[16];
#pragma unroll
  for (int ct = 0; ct < 16; ct++) acc[ct] = (f32x4)(0.f);

  for (int st = 0; st < 8; st++) {
    int k0 = kbase + st * 64;
    __syncthreads();
#pragma unroll
    for (int it = 0; it < 2; it++) {
      int c = tid + it * 256;
      int r = c >> 3, ko = c & 7;
      const float* ap = &A[(size_t)r * IMG_F + k0 + ko * 8];
      float4 f0 = *(const float4*)ap;
      float4 f1 = *(const float4*)(ap + 4);
      int kst = ko >> 2, kq = ko & 3, rt = r >> 4, rr = r & 15;
      int ci = ((kst * 4 + kq) * 4 + (rt ^ kq)) * 16 + rr;
      uint4 u = make_uint4(pk2(f0.x, f0.y), pk2(f0.z, f0.w),
                           pk2(f1.x, f1.y), pk2(f1.z, f1.w));
      *(uint4*)&Al[ci * 8] = u;
    }
    {
      int col4 = tid & 63, koB = tid >> 6;
#pragma unroll
      for (int itb = 0; itb < 2; itb++) {
        int ko = koB + itb * 4;
        const float* bp = &B[(size_t)(k0 + ko * 8) * 1024 + col0 + col4 * 4];
        float fb[8][4];
#pragma unroll
        for (int i2 = 0; i2 < 8; i2++)
          *(float4*)&fb[i2][0] = *(const float4*)(bp + (size_t)i2 * 1024);
        int kst = ko >> 2, kq = ko & 3;
#pragma unroll
        for (int c2 = 0; c2 < 4; c2++) {
          int col = col4 * 4 + c2;
          int ct = col >> 4, colin = col & 15;
          int ci = ((kst * 4 + kq) * 16 + (ct ^ kq)) * 16 + colin;
          uint4 u = make_uint4(pk2(fb[0][c2], fb[1][c2]), pk2(fb[2][c2], fb[3][c2]),
                               pk2(fb[4][c2], fb[5][c2]), pk2(fb[6][c2], fb[7][c2]));
          *(uint4*)&Bl[ci * 8] = u;
        }
      }
    }
    __syncthreads();
#pragma unroll
    for (int kst = 0; kst < 2; kst++) {
      bf16x8 af = *(bf16x8*)&Al[(((kst * 4 + kq_l) * 4 + (w ^ kq_l)) * 16 + rr_l) * 8];
#pragma unroll
      for (int ct = 0; ct < 16; ct++) {
        bf16x8 bf = *(bf16x8*)&Bl[(((kst * 4 + kq_l) * 16 + (ct ^ kq_l)) * 16 + rr_l) * 8];
        acc[ct] = __builtin_amdgcn_mfma_f32_16x16x32_bf16(af, bf, acc[ct], 0, 0, 0);
      }
    }
  }
  float* P = partial + (size_t)blockIdx.y * 64 * 1024;
#pragma unroll
  for (int ct = 0; ct < 16; ct++)
#pragma unroll
    for (int rg = 0; rg < 4; rg++) {
      int row = w * 16 + (l >> 4) * 4 + rg;
      int col = col0 + ct * 16 + (l & 15);
      P[row * 1024 + col] = acc[ct][rg];
    }
}

__global__ __launch_bounds__(256)
void k_img_reduce(const float* __restrict__ partial, const float* __restrict__ bm0,
                  float* __restrict__ tmp1) {
  int i = blockIdx.x * 256 + threadIdx.x;
  float s = bm0[i & 1023];
  for (int ks = 0; ks < KSPLIT; ks++) s += partial[(size_t)ks * 65536 + i];
  tmp1[i] = s;
}

__global__ __launch_bounds__(256)
void k_img_gemm2(const float* __restrict__ T, const float* __restrict__ Wm1,
                 const float* __restrict__ bm1, float* __restrict__ x0) {
  int r = blockIdx.x;
  int c = threadIdx.x & 63;
  int q = threadIdx.x >> 6;
  float acc = 0.f;
#pragma unroll 8
  for (int k = q; k < 1024; k += 4)
    acc = fmaf(T[r * 1024 + k], Wm1[k * 64 + c], acc);
  __shared__ float red[4][64];
  red[q][c] = acc;
  __syncthreads();
  if (q == 0) x0[r * 64 + c] = red[0][c] + red[1][c] + red[2][c] + red[3][c] + bm1[c];
}

// ---------------- node GEMM: C[M,N] = dinv[row]*(act(A[M,128]) @ W[128,N]), bf16
template<int N, bool RELU_BIAS, bool BF16_IN>
__global__ __launch_bounds__(256)
void k_gcn_mfma(const void* __restrict__ Ain, const float* __restrict__ W,
                const float* __restrict__ abias, const float* __restrict__ dinv,
                unsigned short* __restrict__ C, int M) {
  constexpr int NT16 = N / 16;
  __shared__ __align__(16) short Al[1024 * 8];
  __shared__ __align__(16) short Wl[256 * NT16 * 8];
  const int tid = threadIdx.x;
  const int l = tid & 63, w = tid >> 6;
  const int row0 = blockIdx.x * 64;
  const int kq_l = l >> 4, rr_l = l & 15;

#pragma unroll
  for (int it = 0; it < 4; it++) {
    int c = tid + it * 256;
    int r = c >> 4, ko = c & 15;
    int row = row0 + r;
    float f[8] = {0.f, 0.f, 0.f, 0.f, 0.f, 0.f, 0.f, 0.f};
    if (row < M) {
      if constexpr (BF16_IN) {
        const uint* ap = (const uint*)Ain + (size_t)row * 64 + ko * 4;
        uint4 u = *(const uint4*)ap;
        f[0] = bflo(u.x); f[1] = bfhi(u.x); f[2] = bflo(u.y); f[3] = bfhi(u.y);
        f[4] = bflo(u.z); f[5] = bfhi(u.z); f[6] = bflo(u.w); f[7] = bfhi(u.w);
      } else {
        const float* ap = (const float*)Ain + (size_t)row * 128 + ko * 8;
        *(float4*)&f[0] = *(const float4*)ap;
        *(float4*)&f[4] = *(const float4*)(ap + 4);
      }
      if (RELU_BIAS) {
        const float* bp = &abias[ko * 8];
#pragma unroll
        for (int j = 0; j < 8; j++) f[j] = fmaxf(f[j] + bp[j], 0.f);
      }
    }
    int kst = ko >> 2, kq = ko & 3, rt = r >> 4, rr = r & 15;
    int ci = ((kst * 4 + kq) * 4 + (rt ^ kq)) * 16 + rr;
    uint4 u = make_uint4(pk2(f[0], f[1]), pk2(f[2], f[3]),
                         pk2(f[4], f[5]), pk2(f[6], f[7]));
    *(uint4*)&Al[ci * 8] = u;
  }
#pragma unroll
  for (int it = 0; it < (N == 128 ? 2 : 1); it++) {
    int mt = tid + it * 256;
    int col4 = mt % (N / 4), ko = mt / (N / 4);
    float fb[8][4];
#pragma unroll
    for (int i2 = 0; i2 < 8; i2++)
      *(float4*)&fb[i2][0] = *(const float4*)&W[(size_t)(ko * 8 + i2) * N + col4 * 4];
    int kst = ko >> 2, kq = ko & 3;
#pragma unroll
    for (int c2 = 0; c2 < 4; c2++) {
      int col = col4 * 4 + c2;
      int ct = col >> 4, colin = col & 15;
      int ci = ((kst * 4 + kq) * NT16 + (ct ^ kq)) * 16 + colin;
      uint4 u = make_uint4(pk2(fb[0][c2], fb[1][c2]), pk2(fb[2][c2], fb[3][c2]),
                           pk2(fb[4][c2], fb[5][c2]), pk2(fb[6][c2], fb[7][c2]));
      *(uint4*)&Wl[ci * 8] = u;
    }
  }
  __syncthreads();

  f32x4 acc[NT16];
#pragma unroll
  for (int ct = 0; ct < NT16; ct++) acc[ct] = (f32x4)(0.f);
#pragma unroll
  for (int kst = 0; kst < 4; kst++) {
    bf16x8 af = *(bf16x8*)&Al[(((kst * 4 + kq_l) * 4 + (w ^ kq_l)) * 16 + rr_l) * 8];
#pragma unroll
    for (int ct = 0; ct < NT16; ct++) {
      bf16x8 bf = *(bf16x8*)&Wl[(((kst * 4 + kq_l) * NT16 + (ct ^ kq_l)) * 16 + rr_l) * 8];
      acc[ct] = __builtin_amdgcn_mfma_f32_16x16x32_bf16(af, bf, acc[ct], 0, 0, 0);
    }
  }
#pragma unroll
  for (int rg = 0; rg < 4; rg++) {
    int row = row0 + w * 16 + (l >> 4) * 4 + rg;
    if (row < M) {
      float dsc = dinv[row];
#pragma unroll
      for (int ct = 0; ct < NT16; ct++)
        C[(size_t)row * N + ct * 16 + (l & 15)] = f2bf(acc[ct][rg] * dsc);
    }
  }
}

// ---------------- pool (bf16 input, + bias + relu) ----------------
__global__ __launch_bounds__(256)
void k_pool(const unsigned short* __restrict__ h2, const float* __restrict__ b2,
            const int* __restrict__ batch, float* __restrict__ g) {
  int b = blockIdx.x;
  int f = threadIdx.x & 63;
  int q = threadIdx.x >> 6;
  int lo = lower_bound_i(batch, N_NODES, b);
  int hi = lower_bound_i(batch, N_NODES, b + 1);
  float bias = b2[f];
  float acc = 0.f;
  for (int i = lo + q; i < hi; i += 4)
    acc += fmaxf(__uint_as_float((uint)h2[(size_t)i * 64 + f] << 16) + bias, 0.f);
  __shared__ float red[4][64];
  red[q][f] = acc;
  __syncthreads();
  if (q == 0) g[b * 64 + f] = red[0][f] + red[1][f] + red[2][f] + red[3][f];
}

// ---------------- head ----------------
__global__ __launch_bounds__(64)
void k_final(const float* __restrict__ x0, const float* __restrict__ g,
             const float* __restrict__ Wmx, const float* __restrict__ bmx,
             const float* __restrict__ Wfc, const float* __restrict__ bfc,
             float* __restrict__ out) {
  int r = blockIdx.x;
  int c = threadIdx.x;
  __shared__ float sx[128];
  __shared__ float slog[NCLS];
  __shared__ float sred;
  float acc = bmx[c];
#pragma unroll 8
  for (int k = 0; k < 64; k++) acc = fmaf(g[r * 64 + k], Wmx[k * 64 + c], acc);
  sx[64 + c] = acc;
  sx[c] = x0[r * 64 + c];
  __syncthreads();
  float lg = 0.f;
  if (c < NCLS) {
    lg = bfc[c];
#pragma unroll 8
    for (int k = 0; k < 128; k++) lg = fmaf(sx[k], Wfc[k * NCLS + c], lg);
    slog[c] = lg;
  }
  __syncthreads();
  if (c == 0) {
    float m = -1e30f;
    for (int j = 0; j < NCLS; j++) m = fmaxf(m, slog[j]);
    float s = 0.f;
    for (int j = 0; j < NCLS; j++) s += expf(slog[j] - m);
    sred = m + logf(s);
  }
  __syncthreads();
  if (c < NCLS) out[r * NCLS + c] = lg - sred;
}

// ---------------- launch ----------------
extern "C" void kernel_launch(void* const* d_in, const int* in_sizes, int n_in,
                              void* d_out, int out_size, void* d_ws, size_t ws_size,
                              hipStream_t stream) {
  const float* x    = (const float*)d_in[0];
  const int*   edge = (const int*)d_in[1];
  const float* img  = (const float*)d_in[2];
  const int*   batch= (const int*)d_in[3];
  const float* W1   = (const float*)d_in[4];
  const float* b1   = (const float*)d_in[5];
  const float* W2   = (const float*)d_in[6];
  const float* b2   = (const float*)d_in[7];
  const float* Wm0  = (const float*)d_in[8];
  const float* bm0  = (const float*)d_in[9];
  const float* Wm1  = (const float*)d_in[10];
  const float* bm1  = (const float*)d_in[11];
  const float* Wmx  = (const float*)d_in[12];
  const float* bmx  = (const float*)d_in[13];
  const float* Wfc  = (const float*)d_in[14];
  const float* bfc  = (const float*)d_in[15];
  float* out = (float*)d_out;
  const int* srcp = edge;
  const int* dstp = edge + N_EDGES;

  char* ws = (char*)d_ws;
  size_t off = 0;
  auto alloc = [&](size_t bytes) {
    void* p = ws + off;
    off += (bytes + 255) & ~(size_t)255;
    return p;
  };
  int*   gcnt   = (int*)  alloc((size_t)NBUCK * 4);
  int*   deg    = (int*)  alloc((size_t)N_NODES * 4);
  int*   row_lo = (int*)  alloc((size_t)N_NODES * 4);
  float* dinv   = (float*)alloc((size_t)N_NODES * 4);
  uint2* ebuf   = (uint2*)alloc((size_t)NBUCK * BCAP * 8);
  int*   csr    = (int*)  alloc((size_t)NBUCK * BCAP * 4);
  unsigned short* bufA = (unsigned short*)alloc((size_t)N_NODES * 128 * 2);
  size_t bufB_bytes = (size_t)KSPLIT * 65536 * 4;               // >= N_NODES*128*2
  unsigned short* bufB = (unsigned short*)alloc(bufB_bytes);
  float* tmp1   = (float*)alloc(64 * 1024 * 4);
  float* x0     = (float*)alloc(64 * 64 * 4);
  float* g      = (float*)alloc(64 * 64 * 4);
  float* partial = (float*)bufB;  // used only before agg1 writes bufB (stream-ordered)
  (void)ws_size; (void)in_sizes; (void)n_in; (void)out_size;

  // CSR build: bucket pass + per-bucket fill (deg/row_lo/dinv come out of pass 2)
  hipMemsetAsync(gcnt, 0, (size_t)NBUCK * 4, stream);
  k_bucket <<<(N_EDGES + EPB * 256 - 1) / (EPB * 256), 256, 0, stream>>>(
      srcp, dstp, gcnt, ebuf);
  k_binfill<<<NBUCK, 512, 0, stream>>>(ebuf, gcnt, deg, row_lo, dinv, csr);

  // image branch (bf16 MFMA split-K, 4 col-blocks; partials + reduce; no atomics)
  k_img_mfma  <<<dim3(4, KSPLIT), 256, 0, stream>>>(img, Wm0, partial);
  k_img_reduce<<<256, 256, 0, stream>>>(partial, bm0, tmp1);
  k_img_gemm2 <<<64, 256, 0, stream>>>(tmp1, Wm1, bm1, x0);

  // GCN layer 1: h1' = dinv*(x @ W1) in bf16 ; gather-agg (16 lanes/node)
  k_gcn_mfma<128, false, false><<<(N_NODES + 63) / 64, 256, 0, stream>>>(
      x, W1, nullptr, dinv, bufA, N_NODES);
  k_agg_bf16<128, 8><<<(N_NODES + 15) / 16, 256, 0, stream>>>(
      bufA, dinv, row_lo, deg, csr, bufB);

  // GCN layer 2: h2' = dinv*(relu(agg1 + b1) @ W2) in bf16 ; gather-agg
  k_gcn_mfma<64, true, true><<<(N_NODES + 63) / 64, 256, 0, stream>>>(
      bufB, W2, b1, dinv, bufA, N_NODES);
  k_agg_bf16<64, 4><<<(N_NODES + 15) / 16, 256, 0, stream>>>(
      bufA, dinv, row_lo, deg, csr, bufB);

  // pool + head
  k_pool <<<NGR, 256, 0, stream>>>(bufB, b2, batch, g);
  k_final<<<NGR, 64, 0, stream>>>(x0, g, Wmx, bmx, Wfc, bfc, out);
}

// Round 4
// 635.063 us; speedup vs baseline: 1.3195x; 1.0460x over previous
//
#include <hip/hip_runtime.h>
#include <math.h>

#define N_NODES 100000
#define N_EDGES 1600000
#define NGR 64
#define IMG_F 50176
#define NCLS 38
#define KSPLIT 49        // 49 K-slabs of 1024 (49*1024 = 50176 exactly)

// bucketed CSR build (no global atomics, no memset)
#define NBUCK 196        // node buckets of 512 nodes
#define NB_BUCK 391      // pass-1 edge blocks (4096 edges each)
#define CELLCAP 64       // per-(bucket,block) cell capacity (Poisson mean ~21)
#define BCAP 9216        // per-bucket csr capacity (mean 8192, +11 sigma)
#define EPB 16           // edges per thread in bucket pass

#define NB_IMG 196       // 4 col-blocks x 49 K-slabs
#define NB_GCN1 1563     // ceil(100000/64)
#define NB_AGG 6250      // 100000/16

typedef short bf16x8 __attribute__((ext_vector_type(8)));
typedef float f32x4 __attribute__((ext_vector_type(4)));
typedef unsigned int uint;

// fp32 pair -> packed bf16x2 (RNE)
__device__ __forceinline__ uint pk2(float a, float b) {
  uint ua = __float_as_uint(a), ub = __float_as_uint(b);
  ua = (ua + 0x7fffu + ((ua >> 16) & 1u)) >> 16;
  ub = (ub + 0x7fffu + ((ub >> 16) & 1u)) >> 16;
  return ua | (ub << 16);
}
__device__ __forceinline__ unsigned short f2bf(float x) {
  uint u = __float_as_uint(x);
  u = (u + 0x7fffu + ((u >> 16) & 1u)) >> 16;
  return (unsigned short)u;
}
__device__ __forceinline__ float bflo(uint u) { return __uint_as_float(u << 16); }
__device__ __forceinline__ float bfhi(uint u) { return __uint_as_float(u & 0xffff0000u); }

__device__ __forceinline__ int lower_bound_i(const int* __restrict__ a, int n, int v) {
  int lo = 0, hi = n;
  while (lo < hi) { int mid = (lo + hi) >> 1; if (a[mid] < v) lo = mid + 1; else hi = mid; }
  return lo;
}

// ================= role: edge bucketing (pass 1) =================
// Per block: 4096 edges. LDS histogram over 196 buckets, LDS-cursor scatter of
// packed (src | dst9<<17) into fixed per-(bucket,block) cells. Count matrix
// written unconditionally -> no global memset, no global atomics.
__device__ __forceinline__ void role_bucket(char* smemc, int blk,
    const int* __restrict__ src, const int* __restrict__ dst,
    uint* __restrict__ ebuf, int* __restrict__ cnt) {
  int* lhist = (int*)smemc;        // 256 ints
  int* lcur  = lhist + 256;        // 256 ints
  const int t = threadIdx.x;
  lhist[t] = 0; lcur[t] = 0;
  __syncthreads();
  const int e0 = blk * (EPB * 256);
  uint p[EPB]; int k[EPB];
#pragma unroll
  for (int j = 0; j < EPB; j++) {
    int e = e0 + j * 256 + t;
    if (e < N_EDGES) {
      int s = src[e], d = dst[e];
      p[j] = (uint)s | ((uint)(d & 511) << 17);
      k[j] = d >> 9;
      atomicAdd(&lhist[k[j]], 1);
    } else k[j] = -1;
  }
  __syncthreads();
#pragma unroll
  for (int j = 0; j < EPB; j++) {
    if (k[j] >= 0) {
      int pos = atomicAdd(&lcur[k[j]], 1);
      if (pos < CELLCAP)
        ebuf[((size_t)k[j] * NB_BUCK + blk) * CELLCAP + pos] = p[j];
    }
  }
  __syncthreads();
  if (t < NBUCK) {
    int c = lhist[t];
    cnt[t * NB_BUCK + blk] = (c > CELLCAP) ? CELLCAP : c;
  }
}

// ================= role: per-bucket CSR fill (pass 2) =================
// One block per bucket of 512 nodes. Scan the cell-count row, compact-gather
// edges into LDS, histogram+scan -> deg/row_lo/dinv, LDS-cursor csr scatter.
__device__ __forceinline__ void role_binfill(char* smemc, int b,
    const uint* __restrict__ ebuf, const int* __restrict__ cnt,
    int* __restrict__ deg, int* __restrict__ row_lo,
    float* __restrict__ dinv, int* __restrict__ csr) {
  int* scnt = (int*)smemc;            // 512
  int* soff = scnt + 512;             // 512
  int* sdeg = soff + 512;             // 512
  int* scur = sdeg + 512;             // 512
  uint* sedge = (uint*)(scur + 512);  // 9216
  const int t = threadIdx.x;
  const int i0 = t, i1 = t + 256;
  scnt[i0] = (i0 < NB_BUCK) ? cnt[b * NB_BUCK + i0] : 0;
  scnt[i1] = (i1 < NB_BUCK) ? cnt[b * NB_BUCK + i1] : 0;
  __syncthreads();
  int o0 = scnt[i0], o1 = scnt[i1];
  for (int off = 1; off < 512; off <<= 1) {
    int v0 = (i0 >= off) ? scnt[i0 - off] : 0;
    int v1 = (i1 >= off) ? scnt[i1 - off] : 0;
    __syncthreads();
    scnt[i0] += v0; scnt[i1] += v1;
    __syncthreads();
  }
  soff[i0] = scnt[i0] - o0;
  soff[i1] = scnt[i1] - o1;
  sdeg[i0] = 0; sdeg[i1] = 0;
  __syncthreads();
  int total = scnt[511];
  if (total > BCAP) total = BCAP;
  for (int j = t; j < total; j += 256) {
    int lo2 = 0, hi2 = NB_BUCK - 1;   // last cell i with soff[i] <= j
    while (lo2 < hi2) {
      int mid = (lo2 + hi2 + 1) >> 1;
      if (soff[mid] <= j) lo2 = mid; else hi2 = mid - 1;
    }
    int slot = j - soff[lo2];
    if (slot >= CELLCAP) slot = CELLCAP - 1;   // defensive clamp
    uint e = ebuf[((size_t)b * NB_BUCK + lo2) * CELLCAP + slot];
    sedge[j] = e;
    atomicAdd(&sdeg[e >> 17], 1);
  }
  __syncthreads();
  int d0 = sdeg[i0], d1 = sdeg[i1];
  for (int off = 1; off < 512; off <<= 1) {
    int v0 = (i0 >= off) ? sdeg[i0 - off] : 0;
    int v1 = (i1 >= off) ? sdeg[i1 - off] : 0;
    __syncthreads();
    sdeg[i0] += v0; sdeg[i1] += v1;
    __syncthreads();
  }
  int ex0 = sdeg[i0] - d0, ex1 = sdeg[i1] - d1;
  int n0 = b * 512 + i0, n1 = b * 512 + i1;
  if (n0 < N_NODES) { deg[n0] = d0; row_lo[n0] = b * BCAP + ex0; dinv[n0] = rsqrtf((float)d0 + 1.0f); }
  if (n1 < N_NODES) { deg[n1] = d1; row_lo[n1] = b * BCAP + ex1; dinv[n1] = rsqrtf((float)d1 + 1.0f); }
  scur[i0] = ex0; scur[i1] = ex1;
  __syncthreads();
  for (int j = t; j < total; j += 256) {
    uint e = sedge[j];
    int pos = atomicAdd(&scur[e >> 17], 1);
    csr[(size_t)b * BCAP + pos] = (int)(e & 0x1FFFFu);
  }
}

// ================= role: img GEMM (bf16 MFMA split-K) =================
__device__ __forceinline__ void role_img(char* smemc, int b,
    const float* __restrict__ A, const float* __restrict__ B,
    float* __restrict__ partial) {
  short* Al = (short*)smemc;           // 8 KB  (64 rows x 64 k)
  short* Bl = (short*)(smemc + 8192);  // 32 KB (64 k x 256 cols)
  const int tid = threadIdx.x;
  const int l = tid & 63, w = tid >> 6;
  const int col0 = (b & 3) * 256;
  const int kbase = (b >> 2) * 1024;
  const int kq_l = l >> 4, rr_l = l & 15;
  f32x4 acc[16];
#pragma unroll
  for (int ct = 0; ct < 16; ct++) acc[ct] = (f32x4)(0.f);

  for (int st = 0; st < 16; st++) {
    int k0 = kbase + st * 64;
    __syncthreads();
#pragma unroll
    for (int it = 0; it < 2; it++) {
      int c = tid + it * 256;
      int r = c >> 3, ko = c & 7;
      const float* ap = &A[(size_t)r * IMG_F + k0 + ko * 8];
      float4 f0 = *(const float4*)ap;
      float4 f1 = *(const float4*)(ap + 4);
      int kst = ko >> 2, kq = ko & 3, rt = r >> 4, rr = r & 15;
      int ci = ((kst * 4 + kq) * 4 + (rt ^ kq)) * 16 + rr;
      uint4 u = make_uint4(pk2(f0.x, f0.y), pk2(f0.z, f0.w),
                           pk2(f1.x, f1.y), pk2(f1.z, f1.w));
      *(uint4*)&Al[ci * 8] = u;
    }
    {
      int col4 = tid & 63, koB = tid >> 6;
#pragma unroll
      for (int itb = 0; itb < 2; itb++) {
        int ko = koB + itb * 4;
        const float* bp = &B[(size_t)(k0 + ko * 8) * 1024 + col0 + col4 * 4];
        float fb[8][4];
#pragma unroll
        for (int i2 = 0; i2 < 8; i2++)
          *(float4*)&fb[i2][0] = *(const float4*)(bp + (size_t)i2 * 1024);
        int kst = ko >> 2, kq = ko & 3;
#pragma unroll
        for (int c2 = 0; c2 < 4; c2++) {
          int col = col4 * 4 + c2;
          int ct = col >> 4, colin = col & 15;
          int ci = ((kst * 4 + kq) * 16 + (ct ^ kq)) * 16 + colin;
          uint4 u = make_uint4(pk2(fb[0][c2], fb[1][c2]), pk2(fb[2][c2], fb[3][c2]),
                               pk2(fb[4][c2], fb[5][c2]), pk2(fb[6][c2], fb[7][c2]));
          *(uint4*)&Bl[ci * 8] = u;
        }
      }
    }
    __syncthreads();
#pragma unroll
    for (int kst = 0; kst < 2; kst++) {
      bf16x8 af = *(bf16x8*)&Al[(((kst * 4 + kq_l) * 4 + (w ^ kq_l)) * 16 + rr_l) * 8];
#pragma unroll
      for (int ct = 0; ct < 16; ct++) {
        bf16x8 bf = *(bf16x8*)&Bl[(((kst * 4 + kq_l) * 16 + (ct ^ kq_l)) * 16 + rr_l) * 8];
        acc[ct] = __builtin_amdgcn_mfma_f32_16x16x32_bf16(af, bf, acc[ct], 0, 0, 0);
      }
    }
  }
  float* P = partial + (size_t)(b >> 2) * 65536;
#pragma unroll
  for (int ct = 0; ct < 16; ct++)
#pragma unroll
    for (int rg = 0; rg < 4; rg++) {
      int row = w * 16 + (l >> 4) * 4 + rg;
      int col = col0 + ct * 16 + (l & 15);
      P[row * 1024 + col] = acc[ct][rg];
    }
}

// ================= role: node GEMM =================
// C[M,N] = scale(row) * (act(A[M,128]) @ W[128,N]) in bf16.
template<int N, bool RELU_BIAS, bool BF16_IN, bool SCALE>
__device__ __forceinline__ void role_gcn(char* smemc, int row0,
    const void* __restrict__ Ain, const float* __restrict__ W,
    const float* __restrict__ abias, const float* __restrict__ dinv,
    unsigned short* __restrict__ C, int M) {
  constexpr int NT16 = N / 16;
  short* Al = (short*)smemc;            // 16 KB
  short* Wl = (short*)(smemc + 16384);  // 256*NT16*8 shorts
  const int tid = threadIdx.x;
  const int l = tid & 63, w = tid >> 6;
  const int kq_l = l >> 4, rr_l = l & 15;

#pragma unroll
  for (int it = 0; it < 4; it++) {
    int c = tid + it * 256;
    int r = c >> 4, ko = c & 15;
    int row = row0 + r;
    float f[8] = {0.f, 0.f, 0.f, 0.f, 0.f, 0.f, 0.f, 0.f};
    if (row < M) {
      if constexpr (BF16_IN) {
        const uint* ap = (const uint*)Ain + (size_t)row * 64 + ko * 4;
        uint4 u = *(const uint4*)ap;
        f[0] = bflo(u.x); f[1] = bfhi(u.x); f[2] = bflo(u.y); f[3] = bfhi(u.y);
        f[4] = bflo(u.z); f[5] = bfhi(u.z); f[6] = bflo(u.w); f[7] = bfhi(u.w);
      } else {
        const float* ap = (const float*)Ain + (size_t)row * 128 + ko * 8;
        *(float4*)&f[0] = *(const float4*)ap;
        *(float4*)&f[4] = *(const float4*)(ap + 4);
      }
      if (RELU_BIAS) {
        const float* bp = &abias[ko * 8];
#pragma unroll
        for (int j = 0; j < 8; j++) f[j] = fmaxf(f[j] + bp[j], 0.f);
      }
    }
    int kst = ko >> 2, kq = ko & 3, rt = r >> 4, rr = r & 15;
    int ci = ((kst * 4 + kq) * 4 + (rt ^ kq)) * 16 + rr;
    uint4 u = make_uint4(pk2(f[0], f[1]), pk2(f[2], f[3]),
                         pk2(f[4], f[5]), pk2(f[6], f[7]));
    *(uint4*)&Al[ci * 8] = u;
  }
#pragma unroll
  for (int it = 0; it < (N == 128 ? 2 : 1); it++) {
    int mt = tid + it * 256;
    int col4 = mt % (N / 4), ko = mt / (N / 4);
    float fb[8][4];
#pragma unroll
    for (int i2 = 0; i2 < 8; i2++)
      *(float4*)&fb[i2][0] = *(const float4*)&W[(size_t)(ko * 8 + i2) * N + col4 * 4];
    int kst = ko >> 2, kq = ko & 3;
#pragma unroll
    for (int c2 = 0; c2 < 4; c2++) {
      int col = col4 * 4 + c2;
      int ct = col >> 4, colin = col & 15;
      int ci = ((kst * 4 + kq) * NT16 + (ct ^ kq)) * 16 + colin;
      uint4 u = make_uint4(pk2(fb[0][c2], fb[1][c2]), pk2(fb[2][c2], fb[3][c2]),
                           pk2(fb[4][c2], fb[5][c2]), pk2(fb[6][c2], fb[7][c2]));
      *(uint4*)&Wl[ci * 8] = u;
    }
  }
  __syncthreads();

  f32x4 acc[NT16];
#pragma unroll
  for (int ct = 0; ct < NT16; ct++) acc[ct] = (f32x4)(0.f);
#pragma unroll
  for (int kst = 0; kst < 4; kst++) {
    bf16x8 af = *(bf16x8*)&Al[(((kst * 4 + kq_l) * 4 + (w ^ kq_l)) * 16 + rr_l) * 8];
#pragma unroll
    for (int ct = 0; ct < NT16; ct++) {
      bf16x8 bf = *(bf16x8*)&Wl[(((kst * 4 + kq_l) * NT16 + (ct ^ kq_l)) * 16 + rr_l) * 8];
      acc[ct] = __builtin_amdgcn_mfma_f32_16x16x32_bf16(af, bf, acc[ct], 0, 0, 0);
    }
  }
#pragma unroll
  for (int rg = 0; rg < 4; rg++) {
    int row = row0 + w * 16 + (l >> 4) * 4 + rg;
    if (row < M) {
      float dsc = SCALE ? dinv[row] : 1.f;
#pragma unroll
      for (int ct = 0; ct < NT16; ct++)
        C[(size_t)row * N + ct * 16 + (l & 15)] = f2bf(acc[ct][rg] * dsc);
    }
  }
}

// ================= role: GCN aggregation (gather, bf16) =================
// If SRCS: out[n] = bf16(dinv[n]*(dinv[n]*h[n] + sum dinv[s]*h[s]))  (h unscaled)
// else:    out[n] = bf16(dinv[n]*(h'[n] + sum h'[s]))                (h pre-scaled)
template<int F, int VEC, bool SRCS>
__device__ __forceinline__ void role_agg(int nb,
    const unsigned short* __restrict__ h, const float* __restrict__ dinv,
    const int* __restrict__ row_lo, const int* __restrict__ deg,
    const int* __restrict__ csr_src, unsigned short* __restrict__ out) {
  constexpr int L = F / VEC;    // 16
  constexpr int NPB = 256 / L;  // 16
  constexpr int NU = VEC / 2;
  int n = nb * NPB + threadIdx.x / L;
  int lane = threadIdx.x % L;
  if (n >= N_NODES) return;
  const uint* hu = (const uint*)h;
  const int rs = F / 2;
  float dn = dinv[n];
  float acc[VEC];
  uint r0[NU];
  if constexpr (VEC == 8) *(uint4*)r0 = *(const uint4*)&hu[(size_t)n * rs + lane * NU];
  else                    *(uint2*)r0 = *(const uint2*)&hu[(size_t)n * rs + lane * NU];
#pragma unroll
  for (int j = 0; j < NU; j++) {
    float sw = SRCS ? dn : 1.f;
    acc[2*j] = sw * bflo(r0[j]); acc[2*j+1] = sw * bfhi(r0[j]);
  }
  int lo = row_lo[n], hi = lo + deg[n];
  int i = lo;
  for (; i + 4 <= hi; i += 4) {
    int s0 = csr_src[i], s1 = csr_src[i + 1];
    int s2 = csr_src[i + 2], s3 = csr_src[i + 3];
    uint a0[NU], a1[NU], a2[NU], a3[NU];
    if constexpr (VEC == 8) {
      *(uint4*)a0 = *(const uint4*)&hu[(size_t)s0 * rs + lane * NU];
      *(uint4*)a1 = *(const uint4*)&hu[(size_t)s1 * rs + lane * NU];
      *(uint4*)a2 = *(const uint4*)&hu[(size_t)s2 * rs + lane * NU];
      *(uint4*)a3 = *(const uint4*)&hu[(size_t)s3 * rs + lane * NU];
    } else {
      *(uint2*)a0 = *(const uint2*)&hu[(size_t)s0 * rs + lane * NU];
      *(uint2*)a1 = *(const uint2*)&hu[(size_t)s1 * rs + lane * NU];
      *(uint2*)a2 = *(const uint2*)&hu[(size_t)s2 * rs + lane * NU];
      *(uint2*)a3 = *(const uint2*)&hu[(size_t)s3 * rs + lane * NU];
    }
    if constexpr (SRCS) {
      float w0 = dinv[s0], w1 = dinv[s1], w2 = dinv[s2], w3 = dinv[s3];
#pragma unroll
      for (int j = 0; j < NU; j++) {
        acc[2*j]   = fmaf(w0, bflo(a0[j]), fmaf(w1, bflo(a1[j]), fmaf(w2, bflo(a2[j]), fmaf(w3, bflo(a3[j]), acc[2*j]))));
        acc[2*j+1] = fmaf(w0, bfhi(a0[j]), fmaf(w1, bfhi(a1[j]), fmaf(w2, bfhi(a2[j]), fmaf(w3, bfhi(a3[j]), acc[2*j+1]))));
      }
    } else {
#pragma unroll
      for (int j = 0; j < NU; j++) {
        acc[2*j]   += bflo(a0[j]) + bflo(a1[j]) + bflo(a2[j]) + bflo(a3[j]);
        acc[2*j+1] += bfhi(a0[j]) + bfhi(a1[j]) + bfhi(a2[j]) + bfhi(a3[j]);
      }
    }
  }
  for (; i < hi; i++) {
    int s0 = csr_src[i];
    uint a0[NU];
    if constexpr (VEC == 8) *(uint4*)a0 = *(const uint4*)&hu[(size_t)s0 * rs + lane * NU];
    else                    *(uint2*)a0 = *(const uint2*)&hu[(size_t)s0 * rs + lane * NU];
    float w0 = SRCS ? dinv[s0] : 1.f;
#pragma unroll
    for (int j = 0; j < NU; j++) {
      acc[2*j]   = fmaf(w0, bflo(a0[j]), acc[2*j]);
      acc[2*j+1] = fmaf(w0, bfhi(a0[j]), acc[2*j+1]);
    }
  }
  uint o[NU];
#pragma unroll
  for (int j = 0; j < NU; j++) o[j] = pk2(dn * acc[2*j], dn * acc[2*j+1]);
  uint* op = (uint*)out + (size_t)n * rs + lane * NU;
  if constexpr (VEC == 8) *(uint4*)op = *(uint4*)o;
  else                    *(uint2*)op = *(uint2*)o;
}

// ================= fused kernels =================
__global__ __launch_bounds__(256)
void k_front(const float* __restrict__ img, const float* __restrict__ Wm0,
             float* __restrict__ partial,
             const float* __restrict__ x, const float* __restrict__ W1,
             unsigned short* __restrict__ bufA,
             const int* __restrict__ src, const int* __restrict__ dst,
             uint* __restrict__ ebuf, int* __restrict__ cnt) {
  __shared__ __align__(16) char smem[49152];
  int b = blockIdx.x;
  if (b < NB_IMG) {
    role_img(smem, b, img, Wm0, partial);
  } else if (b < NB_IMG + NB_GCN1) {
    role_gcn<128, false, false, false>(smem, (b - NB_IMG) * 64, x, W1, nullptr,
                                       nullptr, bufA, N_NODES);
  } else {
    role_bucket(smem, b - NB_IMG - NB_GCN1, src, dst, ebuf, cnt);
  }
}

__global__ __launch_bounds__(256)
void k_mid(const uint* __restrict__ ebuf, const int* __restrict__ cnt,
           int* __restrict__ deg, int* __restrict__ row_lo,
           float* __restrict__ dinv, int* __restrict__ csr,
           const float* __restrict__ partial, const float* __restrict__ bm0,
           float* __restrict__ tmp1) {
  __shared__ __align__(16) char smem[46080];
  int b = blockIdx.x;
  if (b < NBUCK) {
    role_binfill(smem, b, ebuf, cnt, deg, row_lo, dinv, csr);
  } else {
    int i = (b - NBUCK) * 256 + threadIdx.x;
    float s = bm0[i & 1023];
    for (int ks = 0; ks < KSPLIT; ks++) s += partial[(size_t)ks * 65536 + i];
    tmp1[i] = s;
  }
}

__global__ __launch_bounds__(256)
void k_aggA(const unsigned short* __restrict__ h, const float* __restrict__ dinv,
            const int* __restrict__ row_lo, const int* __restrict__ deg,
            const int* __restrict__ csr, unsigned short* __restrict__ outp,
            const float* __restrict__ T, const float* __restrict__ Wm1,
            const float* __restrict__ bm1, float* __restrict__ x0) {
  __shared__ float red[4][64];
  int b = blockIdx.x;
  if (b < 64) {  // img_gemm2: x0 = T @ Wm1 + bm1
    int r = b;
    int c = threadIdx.x & 63;
    int q = threadIdx.x >> 6;
    float acc = 0.f;
#pragma unroll 8
    for (int k = q; k < 1024; k += 4)
      acc = fmaf(T[r * 1024 + k], Wm1[k * 64 + c], acc);
    red[q][c] = acc;
    __syncthreads();
    if (q == 0) x0[r * 64 + c] = red[0][c] + red[1][c] + red[2][c] + red[3][c] + bm1[c];
  } else {
    role_agg<128, 8, true>(b - 64, h, dinv, row_lo, deg, csr, outp);
  }
}

__global__ __launch_bounds__(256)
void k_gcn2(const unsigned short* __restrict__ Ain, const float* __restrict__ W,
            const float* __restrict__ abias, const float* __restrict__ dinv,
            unsigned short* __restrict__ C) {
  __shared__ __align__(16) char smem[32768];
  role_gcn<64, true, true, true>(smem, blockIdx.x * 64, Ain, W, abias, dinv, C, N_NODES);
}

__global__ __launch_bounds__(256)
void k_agg2(const unsigned short* __restrict__ h, const float* __restrict__ dinv,
            const int* __restrict__ row_lo, const int* __restrict__ deg,
            const int* __restrict__ csr, unsigned short* __restrict__ outp) {
  role_agg<64, 4, false>(blockIdx.x, h, dinv, row_lo, deg, csr, outp);
}

// pool + head, one block per graph (g stays in LDS)
__global__ __launch_bounds__(256)
void k_tail(const unsigned short* __restrict__ h2, const float* __restrict__ b2,
            const int* __restrict__ batch, const float* __restrict__ x0,
            const float* __restrict__ Wmx, const float* __restrict__ bmx,
            const float* __restrict__ Wfc, const float* __restrict__ bfc,
            float* __restrict__ out) {
  int b = blockIdx.x;
  int f = threadIdx.x & 63;
  int q = threadIdx.x >> 6;
  __shared__ float red[4][64];
  __shared__ float sx[128];
  __shared__ float slog[NCLS];
  __shared__ float sred;
  int lo = lower_bound_i(batch, N_NODES, b);
  int hi = lower_bound_i(batch, N_NODES, b + 1);
  float bias = b2[f];
  float acc = 0.f;
  for (int i = lo + q; i < hi; i += 4)
    acc += fmaxf(__uint_as_float((uint)h2[(size_t)i * 64 + f] << 16) + bias, 0.f);
  red[q][f] = acc;
  __syncthreads();
  if (q == 0) red[0][f] = red[0][f] + red[1][f] + red[2][f] + red[3][f];  // g vector
  __syncthreads();
  int c = threadIdx.x;
  if (c < 64) {
    float a2 = bmx[c];
#pragma unroll 8
    for (int k = 0; k < 64; k++) a2 = fmaf(red[0][k], Wmx[k * 64 + c], a2);
    sx[64 + c] = a2;
    sx[c] = x0[b * 64 + c];
  }
  __syncthreads();
  float lg = 0.f;
  if (c < NCLS) {
    lg = bfc[c];
#pragma unroll 8
    for (int k = 0; k < 128; k++) lg = fmaf(sx[k], Wfc[k * NCLS + c], lg);
    slog[c] = lg;
  }
  __syncthreads();
  if (c == 0) {
    float m = -1e30f;
    for (int j = 0; j < NCLS; j++) m = fmaxf(m, slog[j]);
    float s = 0.f;
    for (int j = 0; j < NCLS; j++) s += expf(slog[j] - m);
    sred = m + logf(s);
  }
  __syncthreads();
  if (c < NCLS) out[b * NCLS + c] = lg - sred;
}

// ---------------- launch ----------------
extern "C" void kernel_launch(void* const* d_in, const int* in_sizes, int n_in,
                              void* d_out, int out_size, void* d_ws, size_t ws_size,
                              hipStream_t stream) {
  const float* x    = (const float*)d_in[0];
  const int*   edge = (const int*)d_in[1];
  const float* img  = (const float*)d_in[2];
  const int*   batch= (const int*)d_in[3];
  const float* W1   = (const float*)d_in[4];
  const float* b1   = (const float*)d_in[5];
  const float* W2   = (const float*)d_in[6];
  const float* b2   = (const float*)d_in[7];
  const float* Wm0  = (const float*)d_in[8];
  const float* bm0  = (const float*)d_in[9];
  const float* Wm1  = (const float*)d_in[10];
  const float* bm1  = (const float*)d_in[11];
  const float* Wmx  = (const float*)d_in[12];
  const float* bmx  = (const float*)d_in[13];
  const float* Wfc  = (const float*)d_in[14];
  const float* bfc  = (const float*)d_in[15];
  float* out = (float*)d_out;
  const int* srcp = edge;
  const int* dstp = edge + N_EDGES;

  char* ws = (char*)d_ws;
  size_t off = 0;
  auto alloc = [&](size_t bytes) {
    void* p = ws + off;
    off += (bytes + 255) & ~(size_t)255;
    return p;
  };
  int*   cnt    = (int*)  alloc((size_t)NBUCK * NB_BUCK * 4);
  uint*  ebuf   = (uint*) alloc((size_t)NBUCK * NB_BUCK * CELLCAP * 4);
  int*   csr    = (int*)  alloc((size_t)NBUCK * BCAP * 4);
  int*   deg    = (int*)  alloc((size_t)N_NODES * 4);
  int*   row_lo = (int*)  alloc((size_t)N_NODES * 4);
  float* dinv   = (float*)alloc((size_t)N_NODES * 4);
  unsigned short* bufA = (unsigned short*)alloc((size_t)N_NODES * 128 * 2);
  unsigned short* bufB = (unsigned short*)alloc((size_t)N_NODES * 128 * 2);  // >= partial 12.85 MB
  float* tmp1   = (float*)alloc(64 * 1024 * 4);
  float* x0     = (float*)alloc(64 * 64 * 4);
  float* partial = (float*)bufB;  // used only before agg1 writes bufB (stream-ordered)
  (void)ws_size; (void)in_sizes; (void)n_in; (void)out_size;

  // K1: img GEMM || gcn layer-1 GEMM (unscaled) || edge bucketing
  k_front<<<NB_IMG + NB_GCN1 + NB_BUCK, 256, 0, stream>>>(
      img, Wm0, partial, x, W1, bufA, srcp, dstp, ebuf, cnt);
  // K2: per-bucket CSR fill (deg/row_lo/dinv) || img split-K reduce
  k_mid<<<NBUCK + 256, 256, 0, stream>>>(
      ebuf, cnt, deg, row_lo, dinv, csr, partial, bm0, tmp1);
  // K3: img gemm2 || gather-agg layer 1 (applies dinv on both sides)
  k_aggA<<<64 + NB_AGG, 256, 0, stream>>>(
      bufA, dinv, row_lo, deg, csr, bufB, tmp1, Wm1, bm1, x0);
  // K4: gcn layer-2 GEMM (relu+bias, pre-scaled by dinv)
  k_gcn2<<<NB_GCN1, 256, 0, stream>>>(bufB, W2, b1, dinv, bufA);
  // K5: gather-agg layer 2
  k_agg2<<<NB_AGG, 256, 0, stream>>>(bufA, dinv, row_lo, deg, csr, bufB);
  // K6: pool + head
  k_tail<<<NGR, 256, 0, stream>>>(bufB, b2, batch, x0, Wmx, bmx, Wfc, bfc, out);
}